// Round 1
// baseline (295.562 us; speedup 1.0000x reference)
//
#include <hip/hip_runtime.h>

// ROIAlign (FPN, multi-level) for MI355X.
// Inputs (f32):
//   d_in[0] fm2 [4,256,256,256]  stride 4
//   d_in[1] fm3 [4,128,128,256]  stride 8
//   d_in[2] fm4 [4, 64, 64,256]  stride 16
//   d_in[3] fm5 [4, 32, 32,256]  stride 32
//   d_in[4] rois [4,512,4]  (x1,y1,x2,y2)
// Output (f32): [4,512,256,7,7]

constexpr int S     = 7;     // OUT_SIZE
constexpr int CCH   = 256;   // channels
constexpr int NROI  = 512;
constexpr int BATCH = 4;

__global__ __launch_bounds__(256) void roialign_kernel(
    const float* __restrict__ fm2, const float* __restrict__ fm3,
    const float* __restrict__ fm4, const float* __restrict__ fm5,
    const float* __restrict__ rois, float* __restrict__ out)
{
    const int roi = blockIdx.x;        // 0 .. B*N-1
    const int b   = roi >> 9;          // / 512

    // ---- wave-uniform prologue: box, level select ----
    const float x1 = rois[roi * 4 + 0];
    const float y1 = rois[roi * 4 + 1];
    const float x2 = rois[roi * 4 + 2];
    const float y2 = rois[roi * 4 + 3];

    const float area = (y2 - y1) * (x2 - x1);
    // lvl = round(log(sqrt(area)/224)/log(2) + 4), round-half-even like jnp.round
    const float lraw = logf(sqrtf(area) * (1.0f / 224.0f)) * (1.0f / 0.6931471805599453f) + 4.0f;
    int lvl = (int)rintf(lraw);
    lvl = lvl < 2 ? 2 : (lvl > 5 ? 5 : lvl);

    const float* fm;
    int H;
    float scale;
    if (lvl == 2)      { fm = fm2; H = 256; scale = 0.25f;    }
    else if (lvl == 3) { fm = fm3; H = 128; scale = 0.125f;   }
    else if (lvl == 4) { fm = fm4; H = 64;  scale = 0.0625f;  }
    else               { fm = fm5; H = 32;  scale = 0.03125f; }
    const int W = H;
    fm += (size_t)b * H * W * CCH;

    const float bx1 = x1 * scale;
    const float by1 = y1 * scale;
    const float rw  = fmaxf(x2 * scale - bx1, 1.0f);
    const float rh  = fmaxf(y2 * scale - by1, 1.0f);
    const float stx = rw * (1.0f / S);   // bin width
    const float sty = rh * (1.0f / S);   // bin height

    const int lane  = threadIdx.x & 63;
    const int wv    = threadIdx.x >> 6;  // 0..3
    const int cbase = lane << 2;         // 4 channels per lane (float4)

    float* outb = out + (size_t)roi * (CCH * S * S);

    const float Hf   = (float)H;
    const float Wf   = (float)W;
    const float Hm1  = (float)(H - 1);
    const float Wm1  = (float)(W - 1);

    for (int bin = wv; bin < S * S; bin += 4) {
        const int sy = bin / S;
        const int sx = bin - sy * S;

        float4 acc = make_float4(0.f, 0.f, 0.f, 0.f);

        #pragma unroll
        for (int iy = 0; iy < 2; ++iy) {
            // sample y: y1 + ((k+0.5)/ratio) * (rh/S), k = sy*2+iy
            const float yy = by1 + ((float)(sy * 2 + iy) + 0.5f) * 0.5f * sty;
            if (yy > -1.0f && yy < Hf) {
                const float yc  = fminf(fmaxf(yy, 0.0f), Hm1);
                const int   y0  = (int)floorf(yc);
                const int   y1i = min(y0 + 1, H - 1);
                const float ly  = yc - (float)y0;
                const float hy  = 1.0f - ly;

                #pragma unroll
                for (int ix = 0; ix < 2; ++ix) {
                    const float xx = bx1 + ((float)(sx * 2 + ix) + 0.5f) * 0.5f * stx;
                    if (xx > -1.0f && xx < Wf) {
                        const float xc  = fminf(fmaxf(xx, 0.0f), Wm1);
                        const int   x0  = (int)floorf(xc);
                        const int   x1i = min(x0 + 1, W - 1);
                        const float lx  = xc - (float)x0;
                        const float hx  = 1.0f - lx;

                        const size_t r0 = ((size_t)y0  * W) * CCH;
                        const size_t r1 = ((size_t)y1i * W) * CCH;

                        const float4 f00 = *(const float4*)(fm + r0 + (size_t)x0  * CCH + cbase);
                        const float4 f01 = *(const float4*)(fm + r0 + (size_t)x1i * CCH + cbase);
                        const float4 f10 = *(const float4*)(fm + r1 + (size_t)x0  * CCH + cbase);
                        const float4 f11 = *(const float4*)(fm + r1 + (size_t)x1i * CCH + cbase);

                        const float w00 = hy * hx, w01 = hy * lx;
                        const float w10 = ly * hx, w11 = ly * lx;

                        acc.x += w00 * f00.x + w01 * f01.x + w10 * f10.x + w11 * f11.x;
                        acc.y += w00 * f00.y + w01 * f01.y + w10 * f10.y + w11 * f11.y;
                        acc.z += w00 * f00.z + w01 * f01.z + w10 * f10.z + w11 * f11.z;
                        acc.w += w00 * f00.w + w01 * f01.w + w10 * f10.w + w11 * f11.w;
                    }
                }
            }
        }

        // mean over the 2x2 sub-samples
        const float q = 0.25f;
        float* o = outb + (size_t)cbase * (S * S) + bin;
        o[0 * S * S] = acc.x * q;
        o[1 * S * S] = acc.y * q;
        o[2 * S * S] = acc.z * q;
        o[3 * S * S] = acc.w * q;
    }
}

extern "C" void kernel_launch(void* const* d_in, const int* in_sizes, int n_in,
                              void* d_out, int out_size, void* d_ws, size_t ws_size,
                              hipStream_t stream) {
    const float* fm2  = (const float*)d_in[0];
    const float* fm3  = (const float*)d_in[1];
    const float* fm4  = (const float*)d_in[2];
    const float* fm5  = (const float*)d_in[3];
    const float* rois = (const float*)d_in[4];
    float* out = (float*)d_out;

    roialign_kernel<<<BATCH * NROI, 256, 0, stream>>>(fm2, fm3, fm4, fm5, rois, out);
}

// Round 2
// 107.592 us; speedup vs baseline: 2.7471x; 2.7471x over previous
//
#include <hip/hip_runtime.h>

// ROIAlign (FPN, multi-level) for MI355X.
// Inputs (f32):
//   d_in[0] fm2 [4,256,256,256]  stride 4
//   d_in[1] fm3 [4,128,128,256]  stride 8
//   d_in[2] fm4 [4, 64, 64,256]  stride 16
//   d_in[3] fm5 [4, 32, 32,256]  stride 32
//   d_in[4] rois [4,512,4]  (x1,y1,x2,y2)
// Output (f32): [4,512,256,7,7]
//
// R1 -> R2: fix 5x write amplification (scattered 4B stores at 196B stride)
// by staging the output tile in LDS and writing fully-coalesced float4 runs.
// Each ROI is split into 2 blocks of 128 channels: LDS tile = 49*130 floats
// (~25.5 KB) -> 6 blocks/CU occupancy cap instead of 3 with a 50 KB tile.

constexpr int S     = 7;      // OUT_SIZE
constexpr int SS    = 49;     // S*S
constexpr int CCH   = 256;    // channels
constexpr int NROI  = 512;
constexpr int BATCH = 4;
constexpr int CPAD  = 130;    // LDS floats per bin (128 + pad, even for b64 align)

__global__ __launch_bounds__(256) void roialign_kernel(
    const float* __restrict__ fm2, const float* __restrict__ fm3,
    const float* __restrict__ fm4, const float* __restrict__ fm5,
    const float* __restrict__ rois, float* __restrict__ out)
{
    __shared__ float lds[SS * CPAD];   // 49 * 130 * 4 = 25480 B

    const int blk  = blockIdx.x;       // 0 .. 2*B*N-1
    const int roi  = blk >> 1;         // 0 .. B*N-1
    const int half = blk & 1;          // channel half: 0 -> ch 0..127, 1 -> 128..255
    const int b    = roi >> 9;         // / 512

    // ---- wave-uniform prologue: box, level select ----
    const float x1 = rois[roi * 4 + 0];
    const float y1 = rois[roi * 4 + 1];
    const float x2 = rois[roi * 4 + 2];
    const float y2 = rois[roi * 4 + 3];

    const float area = (y2 - y1) * (x2 - x1);
    const float lraw = logf(sqrtf(area) * (1.0f / 224.0f)) * (1.0f / 0.6931471805599453f) + 4.0f;
    int lvl = (int)rintf(lraw);
    lvl = lvl < 2 ? 2 : (lvl > 5 ? 5 : lvl);

    const float* fm;
    int H;
    float scale;
    if (lvl == 2)      { fm = fm2; H = 256; scale = 0.25f;    }
    else if (lvl == 3) { fm = fm3; H = 128; scale = 0.125f;   }
    else if (lvl == 4) { fm = fm4; H = 64;  scale = 0.0625f;  }
    else               { fm = fm5; H = 32;  scale = 0.03125f; }
    const int W = H;
    fm += (size_t)b * H * W * CCH;

    const float bx1 = x1 * scale;
    const float by1 = y1 * scale;
    const float rw  = fmaxf(x2 * scale - bx1, 1.0f);
    const float rh  = fmaxf(y2 * scale - by1, 1.0f);
    const float stx = rw * (1.0f / S);   // bin width
    const float sty = rh * (1.0f / S);   // bin height

    const int lane = threadIdx.x & 63;
    const int wv   = threadIdx.x >> 6;   // 0..3
    const int coff = (half << 7) + (lane << 1);  // this lane's 2 channels

    const float Hf  = (float)H;
    const float Wf  = (float)W;
    const float Hm1 = (float)(H - 1);
    const float Wm1 = (float)(W - 1);

    // ---- compute phase: bins across waves, 2 channels per lane ----
    for (int bin = wv; bin < SS; bin += 4) {
        const int sy = bin / S;
        const int sx = bin - sy * S;

        float2 acc = make_float2(0.f, 0.f);

        #pragma unroll
        for (int iy = 0; iy < 2; ++iy) {
            const float yy = by1 + ((float)(sy * 2 + iy) + 0.5f) * 0.5f * sty;
            if (yy > -1.0f && yy < Hf) {
                const float yc  = fminf(fmaxf(yy, 0.0f), Hm1);
                const int   y0  = (int)floorf(yc);
                const int   y1i = min(y0 + 1, H - 1);
                const float ly  = yc - (float)y0;
                const float hy  = 1.0f - ly;

                #pragma unroll
                for (int ix = 0; ix < 2; ++ix) {
                    const float xx = bx1 + ((float)(sx * 2 + ix) + 0.5f) * 0.5f * stx;
                    if (xx > -1.0f && xx < Wf) {
                        const float xc  = fminf(fmaxf(xx, 0.0f), Wm1);
                        const int   x0  = (int)floorf(xc);
                        const int   x1i = min(x0 + 1, W - 1);
                        const float lx  = xc - (float)x0;
                        const float hx  = 1.0f - lx;

                        const float* p0 = fm + ((size_t)y0  * W) * CCH + coff;
                        const float* p1 = fm + ((size_t)y1i * W) * CCH + coff;

                        const float2 f00 = *(const float2*)(p0 + (size_t)x0  * CCH);
                        const float2 f01 = *(const float2*)(p0 + (size_t)x1i * CCH);
                        const float2 f10 = *(const float2*)(p1 + (size_t)x0  * CCH);
                        const float2 f11 = *(const float2*)(p1 + (size_t)x1i * CCH);

                        const float w00 = hy * hx, w01 = hy * lx;
                        const float w10 = ly * hx, w11 = ly * lx;

                        acc.x += w00 * f00.x + w01 * f01.x + w10 * f10.x + w11 * f11.x;
                        acc.y += w00 * f00.y + w01 * f01.y + w10 * f10.y + w11 * f11.y;
                    }
                }
            }
        }

        // mean over the 2x2 sub-samples -> LDS tile [bin][c_local]
        *(float2*)(&lds[bin * CPAD + (lane << 1)]) =
            make_float2(acc.x * 0.25f, acc.y * 0.25f);
    }

    __syncthreads();

    // ---- writeback phase: fully coalesced float4 stores ----
    // Output region for this block: out[roi][half*128 .. half*128+127][0..48]
    // = contiguous run of 128*49 = 6272 floats.
    float* oreg = out + (size_t)roi * (CCH * SS) + (size_t)half * (128 * SS);
    const int t = threadIdx.x;

    for (int f0 = t * 4; f0 < 128 * SS; f0 += 256 * 4) {
        float4 v;
        {
            const int c = (f0 + 0) / SS, bn = (f0 + 0) - c * SS;
            v.x = lds[bn * CPAD + c];
        }
        {
            const int c = (f0 + 1) / SS, bn = (f0 + 1) - c * SS;
            v.y = lds[bn * CPAD + c];
        }
        {
            const int c = (f0 + 2) / SS, bn = (f0 + 2) - c * SS;
            v.z = lds[bn * CPAD + c];
        }
        {
            const int c = (f0 + 3) / SS, bn = (f0 + 3) - c * SS;
            v.w = lds[bn * CPAD + c];
        }
        *(float4*)(oreg + f0) = v;
    }
}

extern "C" void kernel_launch(void* const* d_in, const int* in_sizes, int n_in,
                              void* d_out, int out_size, void* d_ws, size_t ws_size,
                              hipStream_t stream) {
    const float* fm2  = (const float*)d_in[0];
    const float* fm3  = (const float*)d_in[1];
    const float* fm4  = (const float*)d_in[2];
    const float* fm5  = (const float*)d_in[3];
    const float* rois = (const float*)d_in[4];
    float* out = (float*)d_out;

    roialign_kernel<<<2 * BATCH * NROI, 256, 0, stream>>>(fm2, fm3, fm4, fm5, rois, out);
}

// Round 3
// 74.162 us; speedup vs baseline: 3.9854x; 1.4508x over previous
//
#include <hip/hip_runtime.h>

// ROIAlign (FPN, multi-level) for MI355X.
// Inputs (f32): fm2 [4,256,256,256] s4 | fm3 [4,128,128,256] s8
//               fm4 [4,64,64,256] s16  | fm5 [4,32,32,256] s32
//               rois [4,512,4] (x1,y1,x2,y2)
// Output (f32): [4,512,256,7,7]
//
// R2 -> R3: kill VALU overhead + widen gathers.
//  - per-block LDS LUT of 14 y / 14 x sample entries (byte row/col offsets,
//    validity-zeroed bilinear weights) -> no per-bin coord math, branchless
//  - 32-bit byte offsets from an SGPR base (one v_add3 per load)
//  - lane carries 4 channels (float4, 16B loads); half-wave per bin ->
//    wave processes 2 bins per pass, 16 dwordx4 loads in two batches of 8

constexpr int S     = 7;
constexpr int SS    = 49;
constexpr int CCH   = 256;
constexpr int NROI  = 512;
constexpr int BATCH = 4;
constexpr int CPAD  = 132;   // floats per bin row in LDS (128 + 4 pad)

__global__ __launch_bounds__(256, 6) void roialign_kernel(
    const float* __restrict__ fm2, const float* __restrict__ fm3,
    const float* __restrict__ fm4, const float* __restrict__ fm5,
    const float* __restrict__ rois, float* __restrict__ out)
{
    __shared__ float    tile[SS * CPAD];            // 25872 B
    __shared__ float    s_wyh[14], s_wyl[14], s_wxh[14], s_wxl[14];
    __shared__ unsigned s_ry0[14], s_ry1[14], s_cx0[14], s_cx1[14];

    const int blk  = blockIdx.x;
    const int roi  = blk >> 1;
    const int half = blk & 1;
    const int b    = roi >> 9;

    // ---- wave-uniform prologue ----
    const float x1  = rois[roi * 4 + 0];
    const float y1v = rois[roi * 4 + 1];
    const float x2  = rois[roi * 4 + 2];
    const float y2v = rois[roi * 4 + 3];

    const float area = (y2v - y1v) * (x2 - x1);
    const float lraw = logf(sqrtf(area) * (1.0f / 224.0f)) * 1.4426950408889634f + 4.0f;
    int lvl = (int)rintf(lraw);
    lvl = lvl < 2 ? 2 : (lvl > 5 ? 5 : lvl);

    const float* fm; int H; float scale;
    if (lvl == 2)      { fm = fm2; H = 256; scale = 0.25f;    }
    else if (lvl == 3) { fm = fm3; H = 128; scale = 0.125f;   }
    else if (lvl == 4) { fm = fm4; H = 64;  scale = 0.0625f;  }
    else               { fm = fm5; H = 32;  scale = 0.03125f; }
    const int W = H;
    fm += (size_t)b * H * W * CCH;

    const float bx1 = x1 * scale, by1 = y1v * scale;
    const float rw  = fmaxf(x2 * scale - bx1, 1.0f);
    const float rh  = fmaxf(y2v * scale - by1, 1.0f);
    const float stx = rw * (1.0f / 7.0f);
    const float sty = rh * (1.0f / 7.0f);

    const int t = threadIdx.x;

    // ---- sample LUT: 14 y entries (wave 0) + 14 x entries (wave 1) ----
    if (t < 14) {
        const int k = t;
        const float yy = by1 + ((float)k + 0.5f) * 0.5f * sty;
        const float Hf = (float)H;
        const bool  v  = (yy > -1.0f) && (yy < Hf);
        const float yc = fminf(fmaxf(yy, 0.0f), Hf - 1.0f);
        const int   y0 = (int)floorf(yc);
        const int   y1i = min(y0 + 1, H - 1);
        const float ly = yc - (float)y0;
        s_wyl[k] = v ? ly : 0.0f;
        s_wyh[k] = v ? 1.0f - ly : 0.0f;
        s_ry0[k] = (unsigned)(y0  * W * (CCH * 4));   // byte offset of row
        s_ry1[k] = (unsigned)(y1i * W * (CCH * 4));
    } else if (t >= 64 && t < 78) {
        const int k = t - 64;
        const float xx = bx1 + ((float)k + 0.5f) * 0.5f * stx;
        const float Wf = (float)W;
        const bool  v  = (xx > -1.0f) && (xx < Wf);
        const float xc = fminf(fmaxf(xx, 0.0f), Wf - 1.0f);
        const int   x0 = (int)floorf(xc);
        const int   x1i = min(x0 + 1, W - 1);
        const float lx = xc - (float)x0;
        s_wxl[k] = v ? lx : 0.0f;
        s_wxh[k] = v ? 1.0f - lx : 0.0f;
        s_cx0[k] = (unsigned)(x0  * (CCH * 4));       // byte offset of col
        s_cx1[k] = (unsigned)(x1i * (CCH * 4));
    }
    __syncthreads();

    // ---- compute: half-wave per bin, 4 channels (float4) per lane ----
    const int lane = t & 63;
    const int wv   = t >> 6;
    const int sub  = lane >> 5;           // which bin of the wave's pair
    const int cl   = lane & 31;           // channel slot (4 ch each)
    const unsigned cb = (unsigned)(((half << 7) | (cl << 2)) << 2);  // byte off in pixel

    const char* __restrict__ fmb = (const char*)fm;   // block-uniform -> SGPR base

    for (int p = wv; p < 25; p += 4) {
        const int binr = 2 * p + sub;                 // 0..49
        const int bin  = binr < 48 ? binr : 48;       // clamp (lane-safe)
        const int sy = bin / 7;
        const int sx = bin - sy * 7;
        const int ky = sy << 1, kx = sx << 1;

        const float hy0 = s_wyh[ky],     ly0 = s_wyl[ky];
        const float hy1 = s_wyh[ky + 1], ly1 = s_wyl[ky + 1];
        const float hx0 = s_wxh[kx],     lx0 = s_wxl[kx];
        const float hx1 = s_wxh[kx + 1], lx1 = s_wxl[kx + 1];
        const unsigned rA = s_ry0[ky],     rB = s_ry1[ky];      // sample-y0 rows
        const unsigned rC = s_ry0[ky + 1], rD = s_ry1[ky + 1];  // sample-y1 rows
        const unsigned cA = s_cx0[kx],     cB = s_cx1[kx];      // sample-x0 cols
        const unsigned cC = s_cx0[kx + 1], cD = s_cx1[kx + 1];  // sample-x1 cols

        float4 acc = make_float4(0.f, 0.f, 0.f, 0.f);

#define LD4(OFF) (*(const float4*)(fmb + (OFF)))
#define ACC4(Wt, F) \
        acc.x = fmaf((Wt), (F).x, acc.x); acc.y = fmaf((Wt), (F).y, acc.y); \
        acc.z = fmaf((Wt), (F).z, acc.z); acc.w = fmaf((Wt), (F).w, acc.w);

        // batch 1: y-sample 0 (rows A,B) x both x-samples (cols A,B,C,D)
        {
            const float4 fAA = LD4(rA + cA + cb);
            const float4 fAB = LD4(rA + cB + cb);
            const float4 fBA = LD4(rB + cA + cb);
            const float4 fBB = LD4(rB + cB + cb);
            const float4 fAC = LD4(rA + cC + cb);
            const float4 fAD = LD4(rA + cD + cb);
            const float4 fBC = LD4(rB + cC + cb);
            const float4 fBD = LD4(rB + cD + cb);
            ACC4(hy0 * hx0, fAA); ACC4(hy0 * lx0, fAB);
            ACC4(ly0 * hx0, fBA); ACC4(ly0 * lx0, fBB);
            ACC4(hy0 * hx1, fAC); ACC4(hy0 * lx1, fAD);
            ACC4(ly0 * hx1, fBC); ACC4(ly0 * lx1, fBD);
        }
        // batch 2: y-sample 1 (rows C,D) x both x-samples
        {
            const float4 fCA = LD4(rC + cA + cb);
            const float4 fCB = LD4(rC + cB + cb);
            const float4 fDA = LD4(rD + cA + cb);
            const float4 fDB = LD4(rD + cB + cb);
            const float4 fCC = LD4(rC + cC + cb);
            const float4 fCD = LD4(rC + cD + cb);
            const float4 fDC = LD4(rD + cC + cb);
            const float4 fDD = LD4(rD + cD + cb);
            ACC4(hy1 * hx0, fCA); ACC4(hy1 * lx0, fCB);
            ACC4(ly1 * hx0, fDA); ACC4(ly1 * lx0, fDB);
            ACC4(hy1 * hx1, fCC); ACC4(hy1 * lx1, fCD);
            ACC4(ly1 * hx1, fDC); ACC4(ly1 * lx1, fDD);
        }
#undef LD4
#undef ACC4

        if (binr < 49) {
            *(float4*)&tile[bin * CPAD + (cl << 2)] = make_float4(
                acc.x * 0.25f, acc.y * 0.25f, acc.z * 0.25f, acc.w * 0.25f);
        }
    }

    __syncthreads();

    // ---- writeback: contiguous 128*49 floats, coalesced float4 stores ----
    float* oreg = out + (size_t)roi * (CCH * SS) + (size_t)half * (128 * SS);
    for (int i = t; i < (128 * SS) / 4; i += 256) {
        const int f0 = i * 4;
        float4 v;
        { const int c = (f0 + 0) / SS, bn = (f0 + 0) - c * SS; v.x = tile[bn * CPAD + c]; }
        { const int c = (f0 + 1) / SS, bn = (f0 + 1) - c * SS; v.y = tile[bn * CPAD + c]; }
        { const int c = (f0 + 2) / SS, bn = (f0 + 2) - c * SS; v.z = tile[bn * CPAD + c]; }
        { const int c = (f0 + 3) / SS, bn = (f0 + 3) - c * SS; v.w = tile[bn * CPAD + c]; }
        *(float4*)(oreg + f0) = v;
    }
}

extern "C" void kernel_launch(void* const* d_in, const int* in_sizes, int n_in,
                              void* d_out, int out_size, void* d_ws, size_t ws_size,
                              hipStream_t stream) {
    const float* fm2  = (const float*)d_in[0];
    const float* fm3  = (const float*)d_in[1];
    const float* fm4  = (const float*)d_in[2];
    const float* fm5  = (const float*)d_in[3];
    const float* rois = (const float*)d_in[4];
    float* out = (float*)d_out;

    roialign_kernel<<<2 * BATCH * NROI, 256, 0, stream>>>(fm2, fm3, fm4, fm5, rois, out);
}